// Round 10
// baseline (198.239 us; speedup 1.0000x reference)
//
#include <hip/hip_runtime.h>

typedef unsigned short u16;
typedef unsigned int   u32;
typedef unsigned long long u64;
typedef __attribute__((ext_vector_type(8))) short    short8;   // 8 bf16 (4 VGPRs)
typedef __attribute__((ext_vector_type(4))) float    floatx4;  // MFMA accumulator
typedef __attribute__((ext_vector_type(4))) _Float16 half4v;   // 4 f16 (2 VGPRs)
typedef __attribute__((ext_vector_type(8))) _Float16 half8v;   // 8 f16 (4 VGPRs)

#define NM 1024
#define NH 16
#define ND 64
#define BB 4
#define LL 1024
#define MM (BB*LL)   // 4096 rows

// ---------- helpers ----------
__device__ __forceinline__ u16 f2bf(float f) {
  union { float f; u32 u; } c; c.f = f;
  u32 u = c.u;
  return (u16)((u + 0x7fffu + ((u >> 16) & 1u)) >> 16);   // RNE
}

__device__ __forceinline__ void cstore(u16* p, float v)  { *p = f2bf(v); }
__device__ __forceinline__ void cstore(float* p, float v){ *p = v; }

__device__ __forceinline__ void load_lds16(const void* g, void* l) {
  __builtin_amdgcn_global_load_lds((const __attribute__((address_space(1))) u32*)g,
                                   (__attribute__((address_space(3))) u32*)l,
                                   16, 0, 0);
}

// V^T key permutation: within each 32-key block, o = q*8 + hi*4 + lo for
// K = 32t + hi*16 + q*4 + lo. This IS the mfma_f32_16x16x32_f16 A-operand
// order (lane quad q holds k=8q+jj <-> physical 16*(jj>>2) + 4q + (jj&3)),
// and concat(pf[2t], pf[2t+1]) is the matching B-operand.
__device__ __forceinline__ int vperm(int K) {
  return (K & ~31) | (((K >> 2) & 3) << 3) | (((K >> 4) & 1) << 2) | (K & 3);
}

// ---------- fp32 -> bf16 convert (y=0..4) + mask bit-pack (y=5), one launch ----
__global__ void conv_all(const float* __restrict__ x,  const float* __restrict__ Wq,
                         const float* __restrict__ Wk, const float* __restrict__ Wv,
                         const float* __restrict__ Wo, const int* __restrict__ m,
                         u16* __restrict__ xb, u16* __restrict__ wcat,
                         u16* __restrict__ wob, u32* __restrict__ mp) {
  const int y = blockIdx.y;
  const int base = blockIdx.x * 256 + threadIdx.x;
  if (y == 5) {                                  // mask pack: 4M int32 -> bits
    const int lane = threadIdx.x & 63;
    #pragma unroll
    for (int t = 0; t < 16; t++) {
      int i = base + t * 262144;
      int v = m[i];
      u64 bits = __ballot(v != 0);
      if (lane == 0) {
        mp[(i >> 5) + 0] = (u32)bits;
        mp[(i >> 5) + 1] = (u32)(bits >> 32);
      }
    }
    return;
  }
  const float* src; u16* dst;
  if      (y == 0) { src = x;  dst = xb; }
  else if (y == 1) { src = Wq; dst = wcat; }
  else if (y == 2) { src = Wk; dst = wcat + NM * NM; }
  else if (y == 3) { src = Wv; dst = wcat + 2 * NM * NM; }
  else             { src = Wo; dst = wob; }
  const int nrep = (y == 0) ? 4 : 1;    // x is 4M elems, weights 1M
  for (int t = 0; t < nrep; t++) {
    int i = (base + t * 262144) * 4;
    float4 v = *(const float4*)(src + i);
    ushort4 o;
    o.x = f2bf(v.x); o.y = f2bf(v.y); o.z = f2bf(v.z); o.w = f2bf(v.w);
    *(ushort4*)(dst + i) = o;
  }
}

// ---------- bf16 GEMM  C[M,N] = A[M,K] @ B[N,K]^T + bias ----------
// m97 structure, BK=32 (r8 post-mortem: BK=64 regressed 41->50us; this is the
// measured-good cadence: 16KB LDS, staging/compute interleave per 32-K slab).
// TRANS_Z2: z==2 slice written transposed, f16, KEY-PERMUTED (vperm) for PV.
template<int TM, int TN, typename OUT_T, bool TRANS_Z2>
__global__ __launch_bounds__(256)
void gemm_bt_kernel(const u16* __restrict__ A,       // M x K
                    const u16* __restrict__ Ball,    // z * (N x K)
                    const float* __restrict__ b0, const float* __restrict__ b1,
                    const float* __restrict__ b2,
                    OUT_T* __restrict__ Call,        // z * (M x N)
                    _Float16* __restrict__ VTout)    // N x M (z==2 only)
{
  constexpr int K = 1024, N = 1024;
  constexpr int NI = TM / 32, NJ = TN / 32;
  constexpr int CH = (TM + TN) / 16;                 // 16-row staging chunks
  const int z = blockIdx.z;
  const u16* Bm = Ball + (size_t)z * N * K;
  const float* bias = (z == 0) ? b0 : ((z == 1) ? b1 : b2);
  OUT_T* C = Call + (size_t)z * MM * N;

  __shared__ u16 S[(TM + TN) * 32];
  u16* As = S;
  u16* Bs = S + TM * 32;

  const int tid = threadIdx.x;
  const int w = tid >> 6, lane = tid & 63, lane15 = lane & 15, quad = lane >> 4;
  const int row0 = blockIdx.x * TM, col0 = blockIdx.y * TN;
  const int wm = (w >> 1) * (TM / 2), wn = (w & 1) * (TN / 2);
  const int sr = lane >> 2, sc = (lane & 3) * 8;   // staging row/col within chunk

  floatx4 acc[NI][NJ];
  const floatx4 zero = {0.f, 0.f, 0.f, 0.f};
  #pragma unroll
  for (int i = 0; i < NI; i++)
    #pragma unroll
    for (int j = 0; j < NJ; j++) acc[i][j] = zero;

  for (int kk = 0; kk < K; kk += 32) {
    __syncthreads();   // WAR: prior tile reads done before restage
    #pragma unroll
    for (int c = 0; c < CH / 4; c++) {
      int g = w * (CH / 4) + c;
      const u16* src;
      if (g * 16 < TM) src = A  + (size_t)(row0 + g * 16 + sr) * K + kk + sc;
      else             src = Bm + (size_t)(col0 + (g * 16 - TM) + sr) * K + kk + sc;
      load_lds16(src, &S[g * 512]);
    }
    __syncthreads();   // drains vmcnt for global_load_lds

    short8 af[NI], bf[NJ];
    #pragma unroll
    for (int i = 0; i < NI; i++)
      af[i] = *(short8*)&As[(wm + i * 16 + lane15) * 32 + quad * 8];
    #pragma unroll
    for (int j = 0; j < NJ; j++)
      bf[j] = *(short8*)&Bs[(wn + j * 16 + lane15) * 32 + quad * 8];
    #pragma unroll
    for (int i = 0; i < NI; i++)
      #pragma unroll
      for (int j = 0; j < NJ; j++)
        acc[i][j] = __builtin_amdgcn_mfma_f32_16x16x32_bf16(af[i], bf[j], acc[i][j], 0, 0, 0);
  }

  // epilogue: C/D layout col=lane&15, row=quad*4+reg  [verified m89/m91]
  #pragma unroll
  for (int i = 0; i < NI; i++) {
    #pragma unroll
    for (int j = 0; j < NJ; j++) {
      int col = col0 + wn + j * 16 + lane15;
      float bv = bias[col];
      if (TRANS_Z2 && z == 2) {
        int row = row0 + wm + i * 16 + quad * 4;      // +r, row%4==0
        int Kk = row & (LL - 1), bb = row & ~(LL - 1);
        int o = vperm(Kk);                             // (Kk&3)==0, +r stays in-place
        half4v hv;
        hv.x = (_Float16)(acc[i][j][0] + bv);
        hv.y = (_Float16)(acc[i][j][1] + bv);
        hv.z = (_Float16)(acc[i][j][2] + bv);
        hv.w = (_Float16)(acc[i][j][3] + bv);
        *(half4v*)&VTout[(size_t)col * MM + bb + o] = hv;
      } else {
        #pragma unroll
        for (int r = 0; r < 4; r++) {
          int row = row0 + wm + i * 16 + quad * 4 + r;
          cstore(&C[(size_t)row * N + col], acc[i][j][r] + bv);
        }
      }
    }
  }
}

// ---------- fused attention v7: double-buffered staging, 1 barrier per kt ----
// 128 q-rows/block, wave owns 2x16 q-groups. K/V fragments hoisted across
// q-groups; PV via mfma_f32_16x16x32_f16 (vperm layout == its A-operand).
// v7 change: two LDS buffers; prefetch(kt+1) issued right after the single
// per-iteration barrier, overlapping the whole compute phase of kt. WAR-safe:
// prefetch at iter kt targets the buffer last read at kt-1, whose reads
// completed before this barrier. 64 KB LDS -> still 2 blocks/CU (= grid).
__global__ __launch_bounds__(256, 2)
void attn_kernel(const u16* __restrict__ Q, const u16* __restrict__ K,
                 const _Float16* __restrict__ VT, const u32* __restrict__ mp,
                 u16* __restrict__ CTX)
{
  __shared__ u16      Ks[2 * 8192];   // per buf: chunk n=(key>>4)*2+s at n*512
  __shared__ _Float16 Vs[2 * 8192];   // per buf: [64 d][128 perm keys], swizzled

  const int tid = threadIdx.x;
  const int w = tid >> 6, lane = tid & 63, lane15 = lane & 15, quad = lane >> 4;
  const int qb = blockIdx.x * 128, bh = blockIdx.y;
  const int b = bh >> 4, h = bh & 15;
  const size_t kvbase = (size_t)(b * LL) * NM + h * ND;  // K rows (bf16)
  const size_t vtbase = (size_t)(h * ND) * MM + (size_t)b * LL;  // VT rows (f16)
  const float scale = 0.03125f;                          // 1/sqrt(1024)

  int q0g[2];
  q0g[0] = qb + w * 16;
  q0g[1] = qb + 64 + w * 16;

  // Q B-fragments per group (lane: n=q=lane15, k=d=quad*8+jj), in regs
  short8 aq[2][2];
  #pragma unroll
  for (int g = 0; g < 2; g++) {
    const u16* qp = Q + (size_t)(b * LL + q0g[g] + lane15) * NM + h * ND + quad * 8;
    aq[g][0] = *(const short8*)(qp);
    aq[g][1] = *(const short8*)(qp + 32);
  }

  // staging lane constants
  const int ksrow = lane >> 2;                    // 0..15 within 16-key group
  const int kscg  = (lane & 3) ^ (ksrow & 3);     // swizzled 16B chunk (of 4)
  const int vsd   = lane >> 4;                    // 0..3 within 4-d group
  const int vscg  = (lane & 15);                  // chunk position 0..15

  // stage one 128-key tile (K + V^T) into buffer `buf`
  auto stage = [&](int kt, int buf) {
    const int k0 = kt * 128;
    u16*      ksb = &Ks[buf * 8192];
    _Float16* vsb = &Vs[buf * 8192];
    #pragma unroll
    for (int t = 0; t < 4; t++) {
      int n = w * 4 + t;
      int s = n & 1, r0 = (n >> 1) * 16;
      int row = r0 + ksrow;
      load_lds16(K + kvbase + (size_t)(k0 + row) * NM + s * 32 + kscg * 8,
                 &ksb[n * 512]);
    }
    #pragma unroll
    for (int t = 0; t < 4; t++) {
      int n = w * 4 + t;
      int d = n * 4 + vsd;
      int cg = vscg ^ (d & 15);
      load_lds16(VT + vtbase + (size_t)d * MM + k0 + cg * 8, &vsb[n * 512]);
    }
  };

  const floatx4 zero = {0.f, 0.f, 0.f, 0.f};
  floatx4 o_acc[2][4] = {{zero, zero, zero, zero}, {zero, zero, zero, zero}};
  float lsum[2] = {0.f, 0.f};

  const u32* mrow0 = mp + (size_t)(b * LL + q0g[0] + lane15) * 32;
  const u32* mrow1 = mp + (size_t)(b * LL + q0g[1] + lane15) * 32;

  stage(0, 0);   // prefetch first tile

  #pragma unroll 1
  for (int kt = 0; kt < 8; kt++) {
    const int buf = kt & 1;
    // mask words (global, into regs; compiler waitcnt covers the use)
    uint4 m4g[2];
    m4g[0] = *(const uint4*)(mrow0 + kt * 4);
    m4g[1] = *(const uint4*)(mrow1 + kt * 4);

    __syncthreads();   // drains stage(kt); also orders reads of buf from kt-1

    if (kt < 7) stage(kt + 1, buf ^ 1);   // overlaps with compute below

    const u16*      ksb = &Ks[buf * 8192];
    const _Float16* vsb = &Vs[buf * 8192];

    // S^T then P fragments; K fragments shared across both q-groups
    half4v pf[2][8];
    #pragma unroll
    for (int j = 0; j < 8; j++) {
      const int ch = (quad ^ (lane15 & 3)) * 8;
      const int kbase = j * 1024 + lane15 * 32 + ch;          // chunk n=2j (s=0)
      const short8 kf0 = *(const short8*)&ksb[kbase];
      const short8 kf1 = *(const short8*)&ksb[kbase + 512];   // chunk 2j+1 (s=1)
      floatx4 sT[2];
      sT[0] = __builtin_amdgcn_mfma_f32_16x16x32_bf16(kf0, aq[0][0], zero, 0, 0, 0);
      sT[1] = __builtin_amdgcn_mfma_f32_16x16x32_bf16(kf0, aq[1][0], zero, 0, 0, 0);
      sT[0] = __builtin_amdgcn_mfma_f32_16x16x32_bf16(kf1, aq[0][1], sT[0], 0, 0, 0);
      sT[1] = __builtin_amdgcn_mfma_f32_16x16x32_bf16(kf1, aq[1][1], sT[1], 0, 0, 0);
      const int sh = (j & 1) * 16 + quad * 4;
      #pragma unroll
      for (int g = 0; g < 2; g++) {
        const uint4 m4 = m4g[g];
        const u32 mw = (j & 2) ? ((j & 4) ? m4.w : m4.y) : ((j & 4) ? m4.z : m4.x);
        float p[4];
        #pragma unroll
        for (int r = 0; r < 4; r++) {
          float e = __expf(sT[g][r] * scale);
          p[r] = ((mw >> (sh + r)) & 1u) ? e : 0.f;
          lsum[g] += p[r];
        }
        const auto lo = __builtin_amdgcn_cvt_pkrtz(p[0], p[1]);
        const auto hi = __builtin_amdgcn_cvt_pkrtz(p[2], p[3]);
        half4v pj;
        pj.x = (_Float16)lo.x; pj.y = (_Float16)lo.y;
        pj.z = (_Float16)hi.x; pj.w = (_Float16)hi.y;
        pf[g][j] = pj;
      }
    }

    // O^T += V^T @ P^T via 16x16x32 f16; V fragments shared across groups
    #pragma unroll
    for (int t = 0; t < 4; t++) {
      const half8v b80 = __builtin_shufflevector(pf[0][2 * t], pf[0][2 * t + 1],
                                                 0, 1, 2, 3, 4, 5, 6, 7);
      const half8v b81 = __builtin_shufflevector(pf[1][2 * t], pf[1][2 * t + 1],
                                                 0, 1, 2, 3, 4, 5, 6, 7);
      #pragma unroll
      for (int jd = 0; jd < 4; jd++) {
        const int d = jd * 16 + lane15;
        const int cidx = (t * 4 + quad) ^ (d & 15);
        const half8v vv = *(const half8v*)&vsb[d * 128 + cidx * 8];
        o_acc[0][jd] = __builtin_amdgcn_mfma_f32_16x16x32_f16(vv, b80, o_acc[0][jd], 0, 0, 0);
        o_acc[1][jd] = __builtin_amdgcn_mfma_f32_16x16x32_f16(vv, b81, o_acc[1][jd], 0, 0, 0);
      }
    }
  }

  // epilogue per group: combine quads' partial sums, then ctx = O / l
  #pragma unroll
  for (int g = 0; g < 2; g++) {
    float ls = lsum[g];
    ls += __shfl_xor(ls, 16);
    ls += __shfl_xor(ls, 32);
    const float inv = 1.0f / ls;
    const size_t obase = (size_t)(b * LL + q0g[g] + lane15) * NM + h * ND;
    #pragma unroll
    for (int jd = 0; jd < 4; jd++) {
      ushort4 o;
      o.x = f2bf(o_acc[g][jd][0] * inv);
      o.y = f2bf(o_acc[g][jd][1] * inv);
      o.z = f2bf(o_acc[g][jd][2] * inv);
      o.w = f2bf(o_acc[g][jd][3] * inv);
      *(ushort4*)(CTX + obase + jd * 16 + quad * 4) = o;
    }
  }
}

// ---------- launch ----------
extern "C" void kernel_launch(void* const* d_in, const int* in_sizes, int n_in,
                              void* d_out, int out_size, void* d_ws, size_t ws_size,
                              hipStream_t stream) {
  const float* x  = (const float*)d_in[0];
  const int*   mk = (const int*)  d_in[1];
  const float* Wq = (const float*)d_in[2]; const float* bq = (const float*)d_in[3];
  const float* Wk = (const float*)d_in[4]; const float* bk = (const float*)d_in[5];
  const float* Wv = (const float*)d_in[6]; const float* bv = (const float*)d_in[7];
  const float* Wo = (const float*)d_in[8]; const float* bo = (const float*)d_in[9];
  float* out = (float*)d_out;

  char* ws = (char*)d_ws;
  u16* xb        = (u16*)(ws);                          // 8 MB
  u16* Wcat      = (u16*)(ws + ((size_t)8  << 20));     // 6 MB (Wq,Wk,Wv)
  u16* Wob       = (u16*)(ws + ((size_t)14 << 20));     // 2 MB
  u16* QKb       = (u16*)(ws + ((size_t)16 << 20));     // 16 MB (Q then K, bf16)
  _Float16* VT   = (_Float16*)(ws + ((size_t)32 << 20));// 8 MB (V^T, f16, perm keys)
  u16* CTX       = (u16*)(ws + ((size_t)40 << 20));     // 8 MB
  u32* mp        = (u32*)(ws + ((size_t)48 << 20));     // 512 KB

  conv_all<<<dim3(1024, 6), 256, 0, stream>>>(x, Wq, Wk, Wv, Wo, mk,
                                              xb, Wcat, Wob, mp);

  // z=0 -> Q (QKb), z=1 -> K (QKb+8MB), z=2 -> VT (transposed f16, permuted)
  gemm_bt_kernel<128, 128, u16, true><<<dim3(32, 8, 3), 256, 0, stream>>>(
      xb, Wcat, bq, bk, bv, QKb, VT);

  attn_kernel<<<dim3(8, 64), 256, 0, stream>>>(
      QKb, QKb + (size_t)MM * NM, VT, mp, CTX);

  // out-projection: 64x128 tiles -> 512 blocks (2/CU)
  gemm_bt_kernel<64, 128, float, false><<<dim3(64, 8, 1), 256, 0, stream>>>(
      CTX, Wob, bo, bo, bo, out, nullptr);
}

// Round 13
// 196.235 us; speedup vs baseline: 1.0102x; 1.0102x over previous
//
#include <hip/hip_runtime.h>

typedef unsigned short u16;
typedef unsigned int   u32;
typedef unsigned long long u64;
typedef __attribute__((ext_vector_type(8))) short    short8;   // 8 bf16 (4 VGPRs)
typedef __attribute__((ext_vector_type(4))) float    floatx4;  // MFMA accumulator
typedef __attribute__((ext_vector_type(4))) _Float16 half4v;   // 4 f16 (2 VGPRs)
typedef __attribute__((ext_vector_type(8))) _Float16 half8v;   // 8 f16 (4 VGPRs)

#define NM 1024
#define NH 16
#define ND 64
#define BB 4
#define LL 1024
#define MM (BB*LL)   // 4096 rows

// ---------- helpers ----------
__device__ __forceinline__ u16 f2bf(float f) {
  union { float f; u32 u; } c; c.f = f;
  u32 u = c.u;
  return (u16)((u + 0x7fffu + ((u >> 16) & 1u)) >> 16);   // RNE
}

__device__ __forceinline__ void cstore(u16* p, float v)  { *p = f2bf(v); }
__device__ __forceinline__ void cstore(float* p, float v){ *p = v; }

__device__ __forceinline__ void load_lds16(const void* g, void* l) {
  __builtin_amdgcn_global_load_lds((const __attribute__((address_space(1))) u32*)g,
                                   (__attribute__((address_space(3))) u32*)l,
                                   16, 0, 0);
}

// V^T key permutation: within each 32-key block, o = q*8 + hi*4 + lo for
// K = 32t + hi*16 + q*4 + lo. This IS the mfma_f32_16x16x32_f16 A-operand
// order (lane quad q holds k=8q+jj <-> physical 16*(jj>>2) + 4q + (jj&3)),
// and concat(pf[2t], pf[2t+1]) is the matching B-operand.
__device__ __forceinline__ int vperm(int K) {
  return (K & ~31) | (((K >> 2) & 3) << 3) | (((K >> 4) & 1) << 2) | (K & 3);
}

// ---------- fp32 -> bf16 convert (y=0..4) + mask bit-pack (y=5), one launch ----
__global__ void conv_all(const float* __restrict__ x,  const float* __restrict__ Wq,
                         const float* __restrict__ Wk, const float* __restrict__ Wv,
                         const float* __restrict__ Wo, const int* __restrict__ m,
                         u16* __restrict__ xb, u16* __restrict__ wcat,
                         u16* __restrict__ wob, u32* __restrict__ mp) {
  const int y = blockIdx.y;
  const int base = blockIdx.x * 256 + threadIdx.x;
  if (y == 5) {                                  // mask pack: 4M int32 -> bits
    const int lane = threadIdx.x & 63;
    #pragma unroll
    for (int t = 0; t < 16; t++) {
      int i = base + t * 262144;
      int v = m[i];
      u64 bits = __ballot(v != 0);
      if (lane == 0) {
        mp[(i >> 5) + 0] = (u32)bits;
        mp[(i >> 5) + 1] = (u32)(bits >> 32);
      }
    }
    return;
  }
  const float* src; u16* dst;
  if      (y == 0) { src = x;  dst = xb; }
  else if (y == 1) { src = Wq; dst = wcat; }
  else if (y == 2) { src = Wk; dst = wcat + NM * NM; }
  else if (y == 3) { src = Wv; dst = wcat + 2 * NM * NM; }
  else             { src = Wo; dst = wob; }
  const int nrep = (y == 0) ? 4 : 1;    // x is 4M elems, weights 1M
  for (int t = 0; t < nrep; t++) {
    int i = (base + t * 262144) * 4;
    float4 v = *(const float4*)(src + i);
    ushort4 o;
    o.x = f2bf(v.x); o.y = f2bf(v.y); o.z = f2bf(v.z); o.w = f2bf(v.w);
    *(ushort4*)(dst + i) = o;
  }
}

// ---------- bf16 GEMM  C[M,N] = A[M,K] @ B[N,K]^T + bias ----------
// m97 structure, BK=32 (r8 post-mortem: BK=64 regressed 41->50us; this is the
// measured-good cadence: 16KB LDS, staging/compute interleave per 32-K slab).
// TRANS_Z2: z==2 slice written transposed, f16, KEY-PERMUTED (vperm) for PV.
template<int TM, int TN, typename OUT_T, bool TRANS_Z2>
__global__ __launch_bounds__(256)
void gemm_bt_kernel(const u16* __restrict__ A,       // M x K
                    const u16* __restrict__ Ball,    // z * (N x K)
                    const float* __restrict__ b0, const float* __restrict__ b1,
                    const float* __restrict__ b2,
                    OUT_T* __restrict__ Call,        // z * (M x N)
                    _Float16* __restrict__ VTout)    // N x M (z==2 only)
{
  constexpr int K = 1024, N = 1024;
  constexpr int NI = TM / 32, NJ = TN / 32;
  constexpr int CH = (TM + TN) / 16;                 // 16-row staging chunks
  const int z = blockIdx.z;
  const u16* Bm = Ball + (size_t)z * N * K;
  const float* bias = (z == 0) ? b0 : ((z == 1) ? b1 : b2);
  OUT_T* C = Call + (size_t)z * MM * N;

  __shared__ u16 S[(TM + TN) * 32];
  u16* As = S;
  u16* Bs = S + TM * 32;

  const int tid = threadIdx.x;
  const int w = tid >> 6, lane = tid & 63, lane15 = lane & 15, quad = lane >> 4;
  const int row0 = blockIdx.x * TM, col0 = blockIdx.y * TN;
  const int wm = (w >> 1) * (TM / 2), wn = (w & 1) * (TN / 2);
  const int sr = lane >> 2, sc = (lane & 3) * 8;   // staging row/col within chunk

  floatx4 acc[NI][NJ];
  const floatx4 zero = {0.f, 0.f, 0.f, 0.f};
  #pragma unroll
  for (int i = 0; i < NI; i++)
    #pragma unroll
    for (int j = 0; j < NJ; j++) acc[i][j] = zero;

  for (int kk = 0; kk < K; kk += 32) {
    __syncthreads();   // WAR: prior tile reads done before restage
    #pragma unroll
    for (int c = 0; c < CH / 4; c++) {
      int g = w * (CH / 4) + c;
      const u16* src;
      if (g * 16 < TM) src = A  + (size_t)(row0 + g * 16 + sr) * K + kk + sc;
      else             src = Bm + (size_t)(col0 + (g * 16 - TM) + sr) * K + kk + sc;
      load_lds16(src, &S[g * 512]);
    }
    __syncthreads();   // drains vmcnt for global_load_lds

    short8 af[NI], bf[NJ];
    #pragma unroll
    for (int i = 0; i < NI; i++)
      af[i] = *(short8*)&As[(wm + i * 16 + lane15) * 32 + quad * 8];
    #pragma unroll
    for (int j = 0; j < NJ; j++)
      bf[j] = *(short8*)&Bs[(wn + j * 16 + lane15) * 32 + quad * 8];
    #pragma unroll
    for (int i = 0; i < NI; i++)
      #pragma unroll
      for (int j = 0; j < NJ; j++)
        acc[i][j] = __builtin_amdgcn_mfma_f32_16x16x32_bf16(af[i], bf[j], acc[i][j], 0, 0, 0);
  }

  // epilogue: C/D layout col=lane&15, row=quad*4+reg  [verified m89/m91]
  #pragma unroll
  for (int i = 0; i < NI; i++) {
    #pragma unroll
    for (int j = 0; j < NJ; j++) {
      int col = col0 + wn + j * 16 + lane15;
      float bv = bias[col];
      if (TRANS_Z2 && z == 2) {
        int row = row0 + wm + i * 16 + quad * 4;      // +r, row%4==0
        int Kk = row & (LL - 1), bb = row & ~(LL - 1);
        int o = vperm(Kk);                             // (Kk&3)==0, +r stays in-place
        half4v hv;
        hv.x = (_Float16)(acc[i][j][0] + bv);
        hv.y = (_Float16)(acc[i][j][1] + bv);
        hv.z = (_Float16)(acc[i][j][2] + bv);
        hv.w = (_Float16)(acc[i][j][3] + bv);
        *(half4v*)&VTout[(size_t)col * MM + bb + o] = hv;
      } else {
        #pragma unroll
        for (int r = 0; r < 4; r++) {
          int row = row0 + wm + i * 16 + quad * 4 + r;
          cstore(&C[(size_t)row * N + col], acc[i][j][r] + bv);
        }
      }
    }
  }
}

// ---------- fused attention v7: double-buffered staging, 1 barrier per kt ----
// 128 q-rows/block, wave owns 2x16 q-groups. K/V fragments hoisted across
// q-groups; PV via mfma_f32_16x16x32_f16 (vperm layout == its A-operand).
// Double-buffer rationale (r12): perf-neutral vs single-buffer (198.2 vs
// 197.5) but structurally race-tolerant — stage(kt+1) writes the buffer last
// READ at kt-1, so the WAR window spans a full compute phase instead of a
// single barrier drain. r12's intermittent post-timing divergence motivated
// preferring this form.
__global__ __launch_bounds__(256, 2)
void attn_kernel(const u16* __restrict__ Q, const u16* __restrict__ K,
                 const _Float16* __restrict__ VT, const u32* __restrict__ mp,
                 u16* __restrict__ CTX)
{
  __shared__ u16      Ks[2 * 8192];   // per buf: chunk n=(key>>4)*2+s at n*512
  __shared__ _Float16 Vs[2 * 8192];   // per buf: [64 d][128 perm keys], swizzled

  const int tid = threadIdx.x;
  const int w = tid >> 6, lane = tid & 63, lane15 = lane & 15, quad = lane >> 4;
  const int qb = blockIdx.x * 128, bh = blockIdx.y;
  const int b = bh >> 4, h = bh & 15;
  const size_t kvbase = (size_t)(b * LL) * NM + h * ND;  // K rows (bf16)
  const size_t vtbase = (size_t)(h * ND) * MM + (size_t)b * LL;  // VT rows (f16)
  const float scale = 0.03125f;                          // 1/sqrt(1024)

  int q0g[2];
  q0g[0] = qb + w * 16;
  q0g[1] = qb + 64 + w * 16;

  // Q B-fragments per group (lane: n=q=lane15, k=d=quad*8+jj), in regs
  short8 aq[2][2];
  #pragma unroll
  for (int g = 0; g < 2; g++) {
    const u16* qp = Q + (size_t)(b * LL + q0g[g] + lane15) * NM + h * ND + quad * 8;
    aq[g][0] = *(const short8*)(qp);
    aq[g][1] = *(const short8*)(qp + 32);
  }

  // staging lane constants
  const int ksrow = lane >> 2;                    // 0..15 within 16-key group
  const int kscg  = (lane & 3) ^ (ksrow & 3);     // swizzled 16B chunk (of 4)
  const int vsd   = lane >> 4;                    // 0..3 within 4-d group
  const int vscg  = (lane & 15);                  // chunk position 0..15

  // stage one 128-key tile (K + V^T) into buffer `buf`
  auto stage = [&](int kt, int buf) {
    const int k0 = kt * 128;
    u16*      ksb = &Ks[buf * 8192];
    _Float16* vsb = &Vs[buf * 8192];
    #pragma unroll
    for (int t = 0; t < 4; t++) {
      int n = w * 4 + t;
      int s = n & 1, r0 = (n >> 1) * 16;
      int row = r0 + ksrow;
      load_lds16(K + kvbase + (size_t)(k0 + row) * NM + s * 32 + kscg * 8,
                 &ksb[n * 512]);
    }
    #pragma unroll
    for (int t = 0; t < 4; t++) {
      int n = w * 4 + t;
      int d = n * 4 + vsd;
      int cg = vscg ^ (d & 15);
      load_lds16(VT + vtbase + (size_t)d * MM + k0 + cg * 8, &vsb[n * 512]);
    }
  };

  const floatx4 zero = {0.f, 0.f, 0.f, 0.f};
  floatx4 o_acc[2][4] = {{zero, zero, zero, zero}, {zero, zero, zero, zero}};
  float lsum[2] = {0.f, 0.f};

  const u32* mrow0 = mp + (size_t)(b * LL + q0g[0] + lane15) * 32;
  const u32* mrow1 = mp + (size_t)(b * LL + q0g[1] + lane15) * 32;

  stage(0, 0);   // prefetch first tile

  #pragma unroll 1
  for (int kt = 0; kt < 8; kt++) {
    const int buf = kt & 1;
    // mask words (global, into regs; compiler waitcnt covers the use)
    uint4 m4g[2];
    m4g[0] = *(const uint4*)(mrow0 + kt * 4);
    m4g[1] = *(const uint4*)(mrow1 + kt * 4);

    __syncthreads();   // drains stage(kt); also orders reads of buf from kt-1

    if (kt < 7) stage(kt + 1, buf ^ 1);   // overlaps with compute below

    const u16*      ksb = &Ks[buf * 8192];
    const _Float16* vsb = &Vs[buf * 8192];

    // S^T then P fragments; K fragments shared across both q-groups
    half4v pf[2][8];
    #pragma unroll
    for (int j = 0; j < 8; j++) {
      const int ch = (quad ^ (lane15 & 3)) * 8;
      const int kbase = j * 1024 + lane15 * 32 + ch;          // chunk n=2j (s=0)
      const short8 kf0 = *(const short8*)&ksb[kbase];
      const short8 kf1 = *(const short8*)&ksb[kbase + 512];   // chunk 2j+1 (s=1)
      floatx4 sT[2];
      sT[0] = __builtin_amdgcn_mfma_f32_16x16x32_bf16(kf0, aq[0][0], zero, 0, 0, 0);
      sT[1] = __builtin_amdgcn_mfma_f32_16x16x32_bf16(kf0, aq[1][0], zero, 0, 0, 0);
      sT[0] = __builtin_amdgcn_mfma_f32_16x16x32_bf16(kf1, aq[0][1], sT[0], 0, 0, 0);
      sT[1] = __builtin_amdgcn_mfma_f32_16x16x32_bf16(kf1, aq[1][1], sT[1], 0, 0, 0);
      const int sh = (j & 1) * 16 + quad * 4;
      #pragma unroll
      for (int g = 0; g < 2; g++) {
        const uint4 m4 = m4g[g];
        const u32 mw = (j & 2) ? ((j & 4) ? m4.w : m4.y) : ((j & 4) ? m4.z : m4.x);
        float p[4];
        #pragma unroll
        for (int r = 0; r < 4; r++) {
          float e = __expf(sT[g][r] * scale);
          p[r] = ((mw >> (sh + r)) & 1u) ? e : 0.f;
          lsum[g] += p[r];
        }
        const auto lo = __builtin_amdgcn_cvt_pkrtz(p[0], p[1]);
        const auto hi = __builtin_amdgcn_cvt_pkrtz(p[2], p[3]);
        half4v pj;
        pj.x = (_Float16)lo.x; pj.y = (_Float16)lo.y;
        pj.z = (_Float16)hi.x; pj.w = (_Float16)hi.y;
        pf[g][j] = pj;
      }
    }

    // O^T += V^T @ P^T via 16x16x32 f16; V fragments shared across groups
    #pragma unroll
    for (int t = 0; t < 4; t++) {
      const half8v b80 = __builtin_shufflevector(pf[0][2 * t], pf[0][2 * t + 1],
                                                 0, 1, 2, 3, 4, 5, 6, 7);
      const half8v b81 = __builtin_shufflevector(pf[1][2 * t], pf[1][2 * t + 1],
                                                 0, 1, 2, 3, 4, 5, 6, 7);
      #pragma unroll
      for (int jd = 0; jd < 4; jd++) {
        const int d = jd * 16 + lane15;
        const int cidx = (t * 4 + quad) ^ (d & 15);
        const half8v vv = *(const half8v*)&vsb[d * 128 + cidx * 8];
        o_acc[0][jd] = __builtin_amdgcn_mfma_f32_16x16x32_f16(vv, b80, o_acc[0][jd], 0, 0, 0);
        o_acc[1][jd] = __builtin_amdgcn_mfma_f32_16x16x32_f16(vv, b81, o_acc[1][jd], 0, 0, 0);
      }
    }
  }

  // epilogue per group: combine quads' partial sums, then ctx = O / l
  #pragma unroll
  for (int g = 0; g < 2; g++) {
    float ls = lsum[g];
    ls += __shfl_xor(ls, 16);
    ls += __shfl_xor(ls, 32);
    const float inv = 1.0f / ls;
    const size_t obase = (size_t)(b * LL + q0g[g] + lane15) * NM + h * ND;
    #pragma unroll
    for (int jd = 0; jd < 4; jd++) {
      ushort4 o;
      o.x = f2bf(o_acc[g][jd][0] * inv);
      o.y = f2bf(o_acc[g][jd][1] * inv);
      o.z = f2bf(o_acc[g][jd][2] * inv);
      o.w = f2bf(o_acc[g][jd][3] * inv);
      *(ushort4*)(CTX + obase + jd * 16 + quad * 4) = o;
    }
  }
}

// ---------- launch ----------
extern "C" void kernel_launch(void* const* d_in, const int* in_sizes, int n_in,
                              void* d_out, int out_size, void* d_ws, size_t ws_size,
                              hipStream_t stream) {
  const float* x  = (const float*)d_in[0];
  const int*   mk = (const int*)  d_in[1];
  const float* Wq = (const float*)d_in[2]; const float* bq = (const float*)d_in[3];
  const float* Wk = (const float*)d_in[4]; const float* bk = (const float*)d_in[5];
  const float* Wv = (const float*)d_in[6]; const float* bv = (const float*)d_in[7];
  const float* Wo = (const float*)d_in[8]; const float* bo = (const float*)d_in[9];
  float* out = (float*)d_out;

  char* ws = (char*)d_ws;
  u16* xb        = (u16*)(ws);                          // 8 MB
  u16* Wcat      = (u16*)(ws + ((size_t)8  << 20));     // 6 MB (Wq,Wk,Wv)
  u16* Wob       = (u16*)(ws + ((size_t)14 << 20));     // 2 MB
  u16* QKb       = (u16*)(ws + ((size_t)16 << 20));     // 16 MB (Q then K, bf16)
  _Float16* VT   = (_Float16*)(ws + ((size_t)32 << 20));// 8 MB (V^T, f16, perm keys)
  u16* CTX       = (u16*)(ws + ((size_t)40 << 20));     // 8 MB
  u32* mp        = (u32*)(ws + ((size_t)48 << 20));     // 512 KB

  conv_all<<<dim3(1024, 6), 256, 0, stream>>>(x, Wq, Wk, Wv, Wo, mk,
                                              xb, Wcat, Wob, mp);

  // z=0 -> Q (QKb), z=1 -> K (QKb+8MB), z=2 -> VT (transposed f16, permuted)
  gemm_bt_kernel<128, 128, u16, true><<<dim3(32, 8, 3), 256, 0, stream>>>(
      xb, Wcat, bq, bk, bv, QKb, VT);

  attn_kernel<<<dim3(8, 64), 256, 0, stream>>>(
      QKb, QKb + (size_t)MM * NM, VT, mp, CTX);

  // out-projection: 64x128 tiles -> 512 blocks (2/CU)
  gemm_bt_kernel<64, 128, float, false><<<dim3(64, 8, 1), 256, 0, stream>>>(
      CTX, Wob, bo, bo, bo, out, nullptr);
}